// Round 2
// baseline (1010.320 us; speedup 1.0000x reference)
//
#include <hip/hip_runtime.h>
#include <math.h>

#define NN 500
#define BB 512
#define BGRP 4            // batch rows per block (amortizes WU reads 4x)
#define BBG (BB / BGRP)   // 128 batch groups
#define NCHUNK 10         // j-dimension split (50 rows per block)
#define JCH (NN / NCHUNK) // 50
#define NPAIR (NN / 2)    // 250 i-pairs per row

using f2 = __attribute__((ext_vector_type(2))) float;

// ---------------- prep: bit-exact f32 threshold + interleaved (W,U*) table ---
// Emulate numpy's float32 pipeline with correctly-rounded f32 ops:
//   uc -> l1=f32(log uc); s=f32(1-uc); l2=f32(log s);
//   z=f32(la+f32(l1-l2)); y=f32(1/f32(1+f32(exp(-z)))); decision = y > 0.5f
__device__ __forceinline__ bool np_decision(float laf, float v) {
    float l1 = (float)log((double)v);
    float s  = 1.0f - v;
    float l2 = (float)log((double)s);
    float logistic = l1 - l2;
    float z  = laf + logistic;
    float e  = (float)exp(-(double)z);
    float d  = 1.0f + e;
    float y  = 1.0f / d;
    return y > 0.5f;
}

// WU[j*NN+i] = { Wt, Ustar } where Wt = (i==j ? 0 : W[i][j]) and Ustar is the
// smallest f32 uc in [LO,HI] whose emulated-f32 decision is TRUE (monotone).
// Window +/-8 ulps around the double-precision threshold prediction
// (empirically within a few ulps); wide-range fallback keeps correctness.
// Also zeroes the completion counters used by the fused last-block reduction
// (workspace is poisoned between iterations; prep always precedes fused).
__global__ void prep_kernel(const float* __restrict__ la,
                            const float* __restrict__ W,
                            float2* __restrict__ WU,
                            int* __restrict__ cnt) {
    int idx = blockIdx.x * blockDim.x + threadIdx.x;
    if (idx < BBG) cnt[idx] = 0;
    if (idx >= NN * NN) return;
    int j = idx / NN;
    int i = idx - j * NN;
    float laf = la[idx];

    const float LO = 1e-6f;
    const float HI = (float)(1.0 - 1e-6);

    float U;
    if (!np_decision(laf, HI)) {
        U = __builtin_inff();               // never true
    } else if (np_decision(laf, LO)) {
        U = 0.0f;                           // always true
    } else {
        // invariant: decision(lo)==false, decision(hi)==true
        unsigned lo = __float_as_uint(LO);
        unsigned hi = __float_as_uint(HI);
        double T  = 1.0 / (1.0 + exp((double)laf));
        float  Tf = fminf(fmaxf((float)T, LO), HI);
        unsigned g = __float_as_uint(Tf);
        unsigned a = (g > lo + 8u) ? g - 8u : lo;
        unsigned b = (g + 8u < hi) ? g + 8u : hi;
        if (a > lo) {
            if (np_decision(laf, __uint_as_float(a))) hi = a; else lo = a;
        }
        if (b > lo && b < hi) {
            if (np_decision(laf, __uint_as_float(b))) hi = b; else lo = b;
        }
        while (hi - lo > 1u) {
            unsigned mid = lo + (hi - lo) / 2u;
            if (np_decision(laf, __uint_as_float(mid))) hi = mid; else lo = mid;
        }
        U = __uint_as_float(hi);
    }
    float w = (i == j) ? 0.0f : W[i * NN + j];
    WU[idx] = make_float2(w, U);
}

// ---------------- fused: partial masked matvec + last-block reduce -----------
// grid = BBG * NCHUNK = 1280 blocks (5 blocks/CU -> 20 waves/CU).
// Block (bg, c) streams u[b0..b0+3, c*50 .. c*50+50, :] with non-temporal
// loads (no reuse; keeps WU resident in L2). One float4 WU load serves 4
// batch rows. The last of the 10 c-chunks for a bg (device-scope counter)
// sums the 10 partials (L2/L3-hot, 80 KB) and writes tanh to out directly —
// removes the separate reduce launch.
__global__ __launch_bounds__(256) void fused_kernel(
        const float* __restrict__ x,
        const float* __restrict__ u,
        const float4* __restrict__ WU4,   // (w,U*) pairs, 2 columns per float4
        float* __restrict__ P,
        int* __restrict__ cnt,
        float* __restrict__ out) {
    __shared__ float xs[BGRP][JCH];
    __shared__ int sh_last;
    const int bid = blockIdx.x;
    const int bg = bid / NCHUNK;
    const int c  = bid - bg * NCHUNK;
    const int b0 = bg * BGRP;
    const int j0 = c * JCH;
    const int t = threadIdx.x;
    if (t < BGRP * JCH) {
        int bl = t / JCH;
        int j  = t - bl * JCH;
        xs[bl][j] = x[(b0 + bl) * NN + j0 + j];
    }
    __syncthreads();

    if (t < NPAIR) {
        const f2* __restrict__ u0 = (const f2*)(u + (size_t)(b0 + 0) * NN * NN);
        const f2* __restrict__ u1 = (const f2*)(u + (size_t)(b0 + 1) * NN * NN);
        const f2* __restrict__ u2 = (const f2*)(u + (size_t)(b0 + 2) * NN * NN);
        const f2* __restrict__ u3 = (const f2*)(u + (size_t)(b0 + 3) * NN * NN);

        float a00 = 0.0f, a01 = 0.0f, a10 = 0.0f, a11 = 0.0f;
        float a20 = 0.0f, a21 = 0.0f, a30 = 0.0f, a31 = 0.0f;
        int k = j0 * NPAIR + t;
#pragma unroll 5
        for (int j = 0; j < JCH; ++j, k += NPAIR) {
            float4 wv = WU4[k];                        // (w0, U0, w1, U1) — L2
            f2 v0 = __builtin_nontemporal_load(u0 + k);
            f2 v1 = __builtin_nontemporal_load(u1 + k);
            f2 v2 = __builtin_nontemporal_load(u2 + k);
            f2 v3 = __builtin_nontemporal_load(u3 + k);
            float x0 = xs[0][j], x1 = xs[1][j], x2 = xs[2][j], x3 = xs[3][j];
            if (v0.x >= wv.y) a00 += wv.x * x0;
            if (v0.y >= wv.w) a01 += wv.z * x0;
            if (v1.x >= wv.y) a10 += wv.x * x1;
            if (v1.y >= wv.w) a11 += wv.z * x1;
            if (v2.x >= wv.y) a20 += wv.x * x2;
            if (v2.y >= wv.w) a21 += wv.z * x2;
            if (v3.x >= wv.y) a30 += wv.x * x3;
            if (v3.y >= wv.w) a31 += wv.z * x3;
        }
        float* Pb = P + ((size_t)c * BB + b0) * NN;
        ((float2*)(Pb + 0 * NN))[t] = make_float2(a00, a01);
        ((float2*)(Pb + 1 * NN))[t] = make_float2(a10, a11);
        ((float2*)(Pb + 2 * NN))[t] = make_float2(a20, a21);
        ((float2*)(Pb + 3 * NN))[t] = make_float2(a30, a31);
    }

    // --- completion protocol: release P stores, count, last block reduces ---
    __threadfence();          // make this thread's P stores device-visible
    __syncthreads();          // all threads of block have fenced
    if (t == 0) {
        int old = __hip_atomic_fetch_add(&cnt[bg], 1, __ATOMIC_ACQ_REL,
                                         __HIP_MEMORY_SCOPE_AGENT);
        sh_last = (old == NCHUNK - 1);
    }
    __syncthreads();
    if (!sh_last) return;
    __threadfence();          // acquire: see other blocks' P stores

    for (int o = t; o < BGRP * NN; o += 256) {
        int bl = o / NN;
        int i  = o - bl * NN;
        const float* Pp = P + (size_t)(b0 + bl) * NN + i;
        float s = Pp[0];
#pragma unroll
        for (int cc = 1; cc < NCHUNK; ++cc)
            s += Pp[(size_t)cc * BB * NN];
        out[(b0 + bl) * NN + i] = tanhf(s);
    }
}

extern "C" void kernel_launch(void* const* d_in, const int* in_sizes, int n_in,
                              void* d_out, int out_size, void* d_ws, size_t ws_size,
                              hipStream_t stream) {
    const float* x  = (const float*)d_in[0];   // [B, N]
    const float* la = (const float*)d_in[1];   // [N, N]
    const float* W  = (const float*)d_in[2];   // [N, N]
    const float* u  = (const float*)d_in[3];   // [B, N, N]
    float* out = (float*)d_out;                // [B, N]

    float2* WU = (float2*)d_ws;                                        // 2,000,000 B
    float*  P  = (float*)((char*)d_ws + (size_t)NN * NN * sizeof(float2)); // 10,240,000 B
    int*    cnt = (int*)((char*)d_ws + (size_t)NN * NN * sizeof(float2)
                                     + (size_t)NCHUNK * BB * NN * sizeof(float)); // 512 B

    int prep_blocks = (NN * NN + 255) / 256;
    prep_kernel<<<prep_blocks, 256, 0, stream>>>(la, W, WU, cnt);
    fused_kernel<<<BBG * NCHUNK, 256, 0, stream>>>(x, u, (const float4*)WU, P, cnt, out);
}

// Round 3
// 686.036 us; speedup vs baseline: 1.4727x; 1.4727x over previous
//
#include <hip/hip_runtime.h>
#include <math.h>

#define NN 500
#define BB 512
#define BGRP 4            // batch rows per block (amortizes WU reads 4x)
#define BBG (BB / BGRP)   // 128 batch groups
#define NCHUNK 20         // j-dimension split (25 rows per block)
#define JCH (NN / NCHUNK) // 25
#define NQ (NN / 4)       // 125 i-quads per row

// ---------------- prep: bit-exact f32 threshold + interleaved (W,U*) table ---
// Emulate numpy's float32 pipeline with correctly-rounded f32 ops:
//   uc -> l1=f32(log uc); s=f32(1-uc); l2=f32(log s);
//   z=f32(la+f32(l1-l2)); y=f32(1/f32(1+f32(exp(-z)))); decision = y > 0.5f
__device__ __forceinline__ bool np_decision(float laf, float v) {
    float l1 = (float)log((double)v);
    float s  = 1.0f - v;
    float l2 = (float)log((double)s);
    float logistic = l1 - l2;
    float z  = laf + logistic;
    float e  = (float)exp(-(double)z);
    float d  = 1.0f + e;
    float y  = 1.0f / d;
    return y > 0.5f;
}

// WU[j*NN+i] = { Wt, Ustar } where Wt = (i==j ? 0 : W[i][j]) and Ustar is the
// smallest f32 uc in [LO,HI] whose emulated-f32 decision is TRUE (monotone).
// Window +/-8 ulps around the double-precision threshold prediction
// (empirically within a few ulps); wide-range fallback keeps correctness.
__global__ void prep_kernel(const float* __restrict__ la,
                            const float* __restrict__ W,
                            float2* __restrict__ WU) {
    int idx = blockIdx.x * blockDim.x + threadIdx.x;
    if (idx >= NN * NN) return;
    int j = idx / NN;
    int i = idx - j * NN;
    float laf = la[idx];

    const float LO = 1e-6f;
    const float HI = (float)(1.0 - 1e-6);

    float U;
    if (!np_decision(laf, HI)) {
        U = __builtin_inff();               // never true
    } else if (np_decision(laf, LO)) {
        U = 0.0f;                           // always true
    } else {
        // invariant: decision(lo)==false, decision(hi)==true
        unsigned lo = __float_as_uint(LO);
        unsigned hi = __float_as_uint(HI);
        double T  = 1.0 / (1.0 + exp((double)laf));
        float  Tf = fminf(fmaxf((float)T, LO), HI);
        unsigned g = __float_as_uint(Tf);
        unsigned a = (g > lo + 8u) ? g - 8u : lo;
        unsigned b = (g + 8u < hi) ? g + 8u : hi;
        if (a > lo) {
            if (np_decision(laf, __uint_as_float(a))) hi = a; else lo = a;
        }
        if (b > lo && b < hi) {
            if (np_decision(laf, __uint_as_float(b))) hi = b; else lo = b;
        }
        while (hi - lo > 1u) {
            unsigned mid = lo + (hi - lo) / 2u;
            if (np_decision(laf, __uint_as_float(mid))) hi = mid; else lo = mid;
        }
        U = __uint_as_float(hi);
    }
    float w = (i == j) ? 0.0f : W[i * NN + j];
    WU[idx] = make_float2(w, U);
}

// ---------------- fused: partial masked matvec, float4 + 2-deep pipeline -----
// grid = BBG * NCHUNK = 2560 blocks of 128 threads (10 blocks/CU, 20 waves/CU).
// Thread t = i-quad (125 active). Per iter: 4x float4 u loads (16B/lane) +
// 2x float4 WU loads; iteration j+1 is explicitly prefetched into registers
// while j is consumed, so >=6 loads stay in flight per thread (round-2 VGPR=36
// showed the compiler wasn't pipelining the 8B version at all).
#define CONSUME(A0_, A1_, A2_, A3_, Wa_, Wb_, jj_)                          \
    do {                                                                     \
        float x0 = xs[0][jj_], x1 = xs[1][jj_];                              \
        float x2 = xs[2][jj_], x3 = xs[3][jj_];                              \
        a00 += (A0_.x >= Wa_.y) ? Wa_.x * x0 : 0.0f;                         \
        a01 += (A0_.y >= Wa_.w) ? Wa_.z * x0 : 0.0f;                         \
        a02 += (A0_.z >= Wb_.y) ? Wb_.x * x0 : 0.0f;                         \
        a03 += (A0_.w >= Wb_.w) ? Wb_.z * x0 : 0.0f;                         \
        a10 += (A1_.x >= Wa_.y) ? Wa_.x * x1 : 0.0f;                         \
        a11 += (A1_.y >= Wa_.w) ? Wa_.z * x1 : 0.0f;                         \
        a12 += (A1_.z >= Wb_.y) ? Wb_.x * x1 : 0.0f;                         \
        a13 += (A1_.w >= Wb_.w) ? Wb_.z * x1 : 0.0f;                         \
        a20 += (A2_.x >= Wa_.y) ? Wa_.x * x2 : 0.0f;                         \
        a21 += (A2_.y >= Wa_.w) ? Wa_.z * x2 : 0.0f;                         \
        a22 += (A2_.z >= Wb_.y) ? Wb_.x * x2 : 0.0f;                         \
        a23 += (A2_.w >= Wb_.w) ? Wb_.z * x2 : 0.0f;                         \
        a30 += (A3_.x >= Wa_.y) ? Wa_.x * x3 : 0.0f;                         \
        a31 += (A3_.y >= Wa_.w) ? Wa_.z * x3 : 0.0f;                         \
        a32 += (A3_.z >= Wb_.y) ? Wb_.x * x3 : 0.0f;                         \
        a33 += (A3_.w >= Wb_.w) ? Wb_.z * x3 : 0.0f;                         \
    } while (0)

__global__ __launch_bounds__(128) void fused_kernel(
        const float* __restrict__ x,
        const float* __restrict__ u,
        const float4* __restrict__ WU4,   // (w,U*) pairs, 2 columns per float4
        float* __restrict__ P) {
    __shared__ float xs[BGRP][JCH];
    const int bid = blockIdx.x;
    const int bg = bid / NCHUNK;
    const int c  = bid - bg * NCHUNK;
    const int b0 = bg * BGRP;
    const int j0 = c * JCH;
    const int t = threadIdx.x;
    if (t < BGRP * JCH) {
        int bl = t / JCH;
        int j  = t - bl * JCH;
        xs[bl][j] = x[(b0 + bl) * NN + j0 + j];
    }
    __syncthreads();
    if (t >= NQ) return;

    // u[b] plane = NN*NN/4 = 62500 float4; row j = 125 float4.
    const float4* __restrict__ u0 = (const float4*)(u + (size_t)(b0 + 0) * NN * NN);
    const float4* __restrict__ u1 = (const float4*)(u + (size_t)(b0 + 1) * NN * NN);
    const float4* __restrict__ u2 = (const float4*)(u + (size_t)(b0 + 2) * NN * NN);
    const float4* __restrict__ u3 = (const float4*)(u + (size_t)(b0 + 3) * NN * NN);

    float a00 = 0.0f, a01 = 0.0f, a02 = 0.0f, a03 = 0.0f;
    float a10 = 0.0f, a11 = 0.0f, a12 = 0.0f, a13 = 0.0f;
    float a20 = 0.0f, a21 = 0.0f, a22 = 0.0f, a23 = 0.0f;
    float a30 = 0.0f, a31 = 0.0f, a32 = 0.0f, a33 = 0.0f;

    int k  = j0 * NQ + t;            // f4 index into u planes
    int kw = j0 * (2 * NQ) + 2 * t;  // f4 index into WU (250 f4 per j-row)

    // prologue: stage j0
    float4 A0 = u0[k], A1 = u1[k], A2 = u2[k], A3 = u3[k];
    float4 Wa = WU4[kw], Wb = WU4[kw + 1];

#pragma unroll 4
    for (int j = 0; j < JCH - 1; ++j) {
        const int k2 = k + NQ, kw2 = kw + 2 * NQ;
        float4 B0 = u0[k2], B1 = u1[k2], B2 = u2[k2], B3 = u3[k2];
        float4 Wc = WU4[kw2], Wd = WU4[kw2 + 1];
        CONSUME(A0, A1, A2, A3, Wa, Wb, j);
        A0 = B0; A1 = B1; A2 = B2; A3 = B3; Wa = Wc; Wb = Wd;
        k = k2; kw = kw2;
    }
    CONSUME(A0, A1, A2, A3, Wa, Wb, JCH - 1);

    float* Pb = P + ((size_t)c * BB + b0) * NN;
    ((float4*)(Pb + 0 * NN))[t] = make_float4(a00, a01, a02, a03);
    ((float4*)(Pb + 1 * NN))[t] = make_float4(a10, a11, a12, a13);
    ((float4*)(Pb + 2 * NN))[t] = make_float4(a20, a21, a22, a23);
    ((float4*)(Pb + 3 * NN))[t] = make_float4(a30, a31, a32, a33);
}

// ---------------- reduce: sum 20 partials + tanh, float4-vectorized ----------
__global__ __launch_bounds__(256) void reduce_kernel(const float* __restrict__ P,
                                                     float* __restrict__ out) {
    int n4 = blockIdx.x * blockDim.x + threadIdx.x;
    if (n4 >= BB * NN / 4) return;
    const int S = BB * NN;
    float4 s = ((const float4*)P)[n4];
#pragma unroll
    for (int cc = 1; cc < NCHUNK; ++cc) {
        float4 p = ((const float4*)(P + (size_t)cc * S))[n4];
        s.x += p.x; s.y += p.y; s.z += p.z; s.w += p.w;
    }
    ((float4*)out)[n4] = make_float4(tanhf(s.x), tanhf(s.y), tanhf(s.z), tanhf(s.w));
}

extern "C" void kernel_launch(void* const* d_in, const int* in_sizes, int n_in,
                              void* d_out, int out_size, void* d_ws, size_t ws_size,
                              hipStream_t stream) {
    const float* x  = (const float*)d_in[0];   // [B, N]
    const float* la = (const float*)d_in[1];   // [N, N]
    const float* W  = (const float*)d_in[2];   // [N, N]
    const float* u  = (const float*)d_in[3];   // [B, N, N]
    float* out = (float*)d_out;                // [B, N]

    float2* WU = (float2*)d_ws;                                        // 2,000,000 B
    float*  P  = (float*)((char*)d_ws + (size_t)NN * NN * sizeof(float2)); // 20,480,000 B

    int prep_blocks = (NN * NN + 255) / 256;
    prep_kernel<<<prep_blocks, 256, 0, stream>>>(la, W, WU);
    fused_kernel<<<BBG * NCHUNK, 128, 0, stream>>>(x, u, (const float4*)WU, P);
    reduce_kernel<<<(BB * NN / 4 + 255) / 256, 256, 0, stream>>>(P, out);
}